// Round 1
// baseline (45.585 us; speedup 1.0000x reference)
//
#include <hip/hip_runtime.h>
#include <hip/hip_bf16.h>

// out = (x + 2) * 3 / 2 == 1.5*x + 3.0  (fp32 elementwise, memory-bound)
// 4096*8192 = 33,554,432 elements = 8,388,608 float4's.

__global__ void affine_f4_kernel(const float4* __restrict__ in,
                                 float4* __restrict__ out,
                                 int n4) {
    int stride = gridDim.x * blockDim.x;
    for (int i = blockIdx.x * blockDim.x + threadIdx.x; i < n4; i += stride) {
        float4 v = in[i];
        float4 r;
        r.x = fmaf(v.x, 1.5f, 3.0f);
        r.y = fmaf(v.y, 1.5f, 3.0f);
        r.z = fmaf(v.z, 1.5f, 3.0f);
        r.w = fmaf(v.w, 1.5f, 3.0f);
        out[i] = r;
    }
}

__global__ void affine_tail_kernel(const float* __restrict__ in,
                                   float* __restrict__ out,
                                   int start, int n) {
    int i = start + blockIdx.x * blockDim.x + threadIdx.x;
    if (i < n) out[i] = fmaf(in[i], 1.5f, 3.0f);
}

extern "C" void kernel_launch(void* const* d_in, const int* in_sizes, int n_in,
                              void* d_out, int out_size, void* d_ws, size_t ws_size,
                              hipStream_t stream) {
    const float* in = (const float*)d_in[0];
    float* out = (float*)d_out;
    int n = in_sizes[0];

    int n4 = n >> 2;  // float4 count
    const int block = 256;
    int grid = (n4 + block - 1) / block;
    if (grid > 2048) grid = 2048;   // grid-stride the rest (G11)
    if (grid < 1) grid = 1;

    affine_f4_kernel<<<grid, block, 0, stream>>>(
        (const float4*)in, (float4*)out, n4);

    int tail_start = n4 << 2;
    int tail = n - tail_start;
    if (tail > 0) {
        affine_tail_kernel<<<1, 64, 0, stream>>>(in, out, tail_start, n);
    }
}

// Round 3
// 42.529 us; speedup vs baseline: 1.0719x; 1.0719x over previous
//
#include <hip/hip_runtime.h>
#include <hip/hip_bf16.h>

// out = (x + 2) * 3 / 2 == 1.5*x + 3.0  (fp32 elementwise, memory-bound)
// 4096*8192 = 33,554,432 elements = 8,388,608 float4's.
//
// R2 fix: use a native clang ext_vector float4 (__builtin_nontemporal_store
// rejects HIP's struct-wrapped HIP_vector_type). Theory unchanged from R1:
// NT stores keep the 128 MiB input L3-resident across graph replays.

typedef float f32x4 __attribute__((ext_vector_type(4)));

__global__ void affine_f4_nt_kernel(const f32x4* __restrict__ in,
                                    f32x4* __restrict__ out,
                                    int n4) {
    int i = blockIdx.x * blockDim.x + threadIdx.x;
    if (i < n4) {
        f32x4 v = in[i];
        f32x4 r;
        r.x = fmaf(v.x, 1.5f, 3.0f);
        r.y = fmaf(v.y, 1.5f, 3.0f);
        r.z = fmaf(v.z, 1.5f, 3.0f);
        r.w = fmaf(v.w, 1.5f, 3.0f);
        __builtin_nontemporal_store(r, &out[i]);
    }
}

__global__ void affine_tail_kernel(const float* __restrict__ in,
                                   float* __restrict__ out,
                                   int start, int n) {
    int i = start + blockIdx.x * blockDim.x + threadIdx.x;
    if (i < n) out[i] = fmaf(in[i], 1.5f, 3.0f);
}

extern "C" void kernel_launch(void* const* d_in, const int* in_sizes, int n_in,
                              void* d_out, int out_size, void* d_ws, size_t ws_size,
                              hipStream_t stream) {
    const float* in = (const float*)d_in[0];
    float* out = (float*)d_out;
    int n = in_sizes[0];

    int n4 = n >> 2;  // float4 count
    const int block = 256;
    int grid = (n4 + block - 1) / block;   // one float4 per thread
    if (grid < 1) grid = 1;

    affine_f4_nt_kernel<<<grid, block, 0, stream>>>(
        (const f32x4*)in, (f32x4*)out, n4);

    int tail_start = n4 << 2;
    int tail = n - tail_start;
    if (tail > 0) {
        affine_tail_kernel<<<1, 64, 0, stream>>>(in, out, tail_start, n);
    }
}